// Round 6
// baseline (164.527 us; speedup 1.0000x reference)
//
#include <hip/hip_runtime.h>
#include <hip/hip_bf16.h>

#define HDIM 256
#define HPDIM 128

typedef short bf8 __attribute__((ext_vector_type(8)));   // 8 bf16 in 4 VGPRs
typedef float f32x4 __attribute__((ext_vector_type(4)));

__device__ inline unsigned pkbf2(float a, float b) {
  float2 f; f.x = a; f.y = b;
  __hip_bfloat162 h = __float22bfloat162_rn(f);          // v_cvt_pk_bf16_f32 (RNE)
  unsigned u; __builtin_memcpy(&u, &h, 4); return u;
}
__device__ inline unsigned short bfbits(float v) {
  __hip_bfloat16 h = __float2bfloat16(v);
  unsigned short u; __builtin_memcpy(&u, &h, 2); return u;
}
__device__ inline uint4 pack8u(float4 a, float4 b) {
  uint4 r;
  r.x = pkbf2(a.x, a.y); r.y = pkbf2(a.z, a.w);
  r.z = pkbf2(b.x, b.y); r.w = pkbf2(b.z, b.w);
  return r;
}
__device__ inline float fast_tanh(float x) {
  float t = __expf(2.0f * x);
  return 1.0f - 2.0f * __builtin_amdgcn_rcpf(t + 1.0f);
}
// gather 8 consecutive fp32 weights -> bf16 MFMA fragment
__device__ inline bf8 wfrag(const float* __restrict__ s) {
  float4 a = *(const float4*)s, b = *(const float4*)(s + 4);
  uint4 u = pack8u(a, b);
  bf8 r; __builtin_memcpy(&r, &u, 16); return r;
}
// non-temporal float4 load via native clang vector type (builtin rejects
// HIP_vector_type). Slab is read-once -> keep it out of L2 so the reused
// wv operand (msgTT/g1TT, 1 MB) stays L2-resident.
__device__ inline float4 ntload4(const float* p) {
  f32x4 v = __builtin_nontemporal_load((const f32x4*)p);
  float4 r; r.x = v[0]; r.y = v[1]; r.z = v[2]; r.w = v[3]; return r;
}

// ---------------- Kernel 0: prep -----------------------------------------
// blocks 0..63 : front MLP (self-gathered weight fragments) -> x3f
// blocks 64..79: msg[b][h] -> msgTT[(h>>2)*4096 + b*4 + (h&3)]
__global__ __launch_bounds__(256) void k_prep(
    const float* __restrict__ h0, const float* __restrict__ htv,
    const float* __restrict__ cp,
    const float* __restrict__ w1, const float* __restrict__ w2,
    const float* __restrict__ w3, const float* __restrict__ msg,
    short* __restrict__ x3f, float* __restrict__ msgTT) {
  const int t = threadIdx.x;
  const int bx = blockIdx.x;

  if (bx >= 64) {                      // ---- msg transpose: 16 blocks
    const int b0 = (bx - 64) * 64;
    #pragma unroll
    for (int it = 0; it < 16; ++it) {
      int u = it * 256 + t;            // 4096 (g,b) float4 pairs
      int bl = u & 63, g = u >> 6;
      float4 v = *(const float4*)(msg + (size_t)(b0 + bl) * HDIM + g * 4);
      *(float4*)(msgTT + (size_t)g * 4096 + (b0 + bl) * 4) = v;   // coalesced write
    }
    return;
  }

  // ---- front MLP: 64 blocks x 16 b ----
  __shared__ char hbuf[8192];    // 16 x 256 bf16, swizzled 16B chunks
  __shared__ char xa[4096];      // 16 x 128 bf16, swizzled
  __shared__ char xb[4096];
  const int wave = t >> 6, lane = t & 63;
  const int r16 = lane & 15, quad = lane >> 4;
  const int b0 = bx * 16;
  const float cc = fminf(fmaxf(cp[0], 0.f), 1.f);

  // stage h = cc*h0+(1-cc)*ht (16x256)
  #pragma unroll
  for (int it = 0; it < 2; ++it) {
    int flat = it * 2048 + t * 8;
    int row = flat >> 8, col = flat & 255, kb = col >> 3;
    int gi = (b0 + row) * HDIM + col;
    float4 a = *(const float4*)(h0 + gi);
    float4 b = *(const float4*)(htv + gi);
    float4 va, vb;
    va.x = cc*a.x + (1.f-cc)*b.x; va.y = cc*a.y + (1.f-cc)*b.y;
    va.z = cc*a.z + (1.f-cc)*b.z; va.w = cc*a.w + (1.f-cc)*b.w;
    a = *(const float4*)(h0 + gi + 4); b = *(const float4*)(htv + gi + 4);
    vb.x = cc*a.x + (1.f-cc)*b.x; vb.y = cc*a.y + (1.f-cc)*b.y;
    vb.z = cc*a.z + (1.f-cc)*b.z; vb.w = cc*a.w + (1.f-cc)*b.w;
    *(uint4*)(hbuf + row*512 + ((kb ^ (row & 7)) << 4)) = pack8u(va, vb);
  }
  __syncthreads();

  // layer 1: [16 x 256] @ w1^T -> xa
  {
    f32x4 acc[2] = {};
    #pragma unroll
    for (int ks = 0; ks < 8; ++ks) {
      bf8 af = *(bf8*)(hbuf + r16*512 + (((ks*4 + quad) ^ (r16 & 7)) << 4));
      #pragma unroll
      for (int nt = 0; nt < 2; ++nt) {
        bf8 bw_ = wfrag(w1 + ((wave*2 + nt)*16 + r16) * 256 + ks*32 + quad*8);
        acc[nt] = __builtin_amdgcn_mfma_f32_16x16x32_bf16(af, bw_, acc[nt], 0, 0, 0);
      }
    }
    #pragma unroll
    for (int nt = 0; nt < 2; ++nt)
      #pragma unroll
      for (int i = 0; i < 4; ++i) {
        int row = quad*4 + i, col = wave*32 + nt*16 + r16;
        *(unsigned short*)(xa + row*256 + (((col >> 3) ^ (row & 7)) << 4) + ((col & 7) << 1))
            = bfbits(fast_tanh(acc[nt][i]));
      }
  }
  __syncthreads();
  // layer 2: xa @ w2^T -> xb
  {
    f32x4 acc[2] = {};
    #pragma unroll
    for (int ks = 0; ks < 4; ++ks) {
      bf8 af = *(bf8*)(xa + r16*256 + (((ks*4 + quad) ^ (r16 & 7)) << 4));
      #pragma unroll
      for (int nt = 0; nt < 2; ++nt) {
        bf8 bw_ = wfrag(w2 + ((wave*2 + nt)*16 + r16) * 128 + ks*32 + quad*8);
        acc[nt] = __builtin_amdgcn_mfma_f32_16x16x32_bf16(af, bw_, acc[nt], 0, 0, 0);
      }
    }
    #pragma unroll
    for (int nt = 0; nt < 2; ++nt)
      #pragma unroll
      for (int i = 0; i < 4; ++i) {
        int row = quad*4 + i, col = wave*32 + nt*16 + r16;
        *(unsigned short*)(xb + row*256 + (((col >> 3) ^ (row & 7)) << 4) + ((col & 7) << 1))
            = bfbits(fast_tanh(acc[nt][i]));
      }
  }
  __syncthreads();
  // layer 3: xb @ w3^T -> xa
  {
    f32x4 acc[2] = {};
    #pragma unroll
    for (int ks = 0; ks < 4; ++ks) {
      bf8 af = *(bf8*)(xb + r16*256 + (((ks*4 + quad) ^ (r16 & 7)) << 4));
      #pragma unroll
      for (int nt = 0; nt < 2; ++nt) {
        bf8 bw_ = wfrag(w3 + ((wave*2 + nt)*16 + r16) * 128 + ks*32 + quad*8);
        acc[nt] = __builtin_amdgcn_mfma_f32_16x16x32_bf16(af, bw_, acc[nt], 0, 0, 0);
      }
    }
    #pragma unroll
    for (int nt = 0; nt < 2; ++nt)
      #pragma unroll
      for (int i = 0; i < 4; ++i) {
        int row = quad*4 + i, col = wave*32 + nt*16 + r16;
        *(unsigned short*)(xa + row*256 + (((col >> 3) ^ (row & 7)) << 4) + ((col & 7) << 1))
            = bfbits(fast_tanh(acc[nt][i]));
      }
  }
  __syncthreads();
  // dump xa -> x3f in B-fragment order
  {
    int ks = t >> 6, l = t & 63, q2 = l >> 4, rr = l & 15;
    uint4 d = *(uint4*)(xa + rr*256 + (((ks*4 + q2) ^ (rr & 7)) << 4));
    *(uint4*)(x3f + (size_t)((bx*4 + ks)*64 + l)*8) = d;
  }
}

// ---------------- Kernel 1/2: fused hypernetwork GEMM --------------------
// PHASE 0: g1TT[k,b] = tanh( sum_h msgTT[h,b] * (fc4[kcol*256+h,:] . x3[b,:]) )
// PHASE 1: out[b,kcol] =     sum_k g1TT[k,b]  * (fc4[65536+kcol*256+k,:] . x3[b,:])
// ONE 1024-thread block per kcol (grid 256 = 1/CU, 16 waves = 4/SIMD TLP).
// xf pinned via opaque asm def (blocks rematerialization — the round-0/3
// bottleneck). Slab staged with NON-TEMPORAL loads: the 32 MB/phase stream
// was evicting the 1 MB reused wv operand (msgTT/g1TT) from each XCD L2,
// pushing 256 MB/phase of wv reuse out to L3 (~2x cost). nt keeps wv L2-hot.
template<int PHASE>
__global__ __launch_bounds__(1024, 4) void k_hyper(
    const short* __restrict__ x3f, const float* __restrict__ wTT,
    const float* __restrict__ fc4, float* __restrict__ outp) {
  __shared__ char lds[65536];              // 256 rows x 256 B, xor-swizzled
  const int bxs = blockIdx.x;
  const int kcol = ((bxs & 7) << 5) | (bxs >> 3);   // bijective XCD grouping
  const int t = threadIdx.x, wave = t >> 6, lane = t & 63;
  const int r16 = lane & 15, quad = lane >> 4;
  const int bw = wave * 64;                // this wave's 64-b slice

  // x3 B-fragments (16 x b128 per thread = 64 VGPRs), pinned live
  bf8 xf[4][4];
  #pragma unroll
  for (int nt = 0; nt < 4; ++nt)
    #pragma unroll
    for (int ks = 0; ks < 4; ++ks)
      xf[nt][ks] = *(const bf8*)(x3f +
          (size_t)(((wave*4 + nt)*4 + ks)*64 + lane)*8);
  #pragma unroll
  for (int nt = 0; nt < 4; ++nt)
    #pragma unroll
    for (int ks = 0; ks < 4; ++ks)
      asm volatile("" : "+v"(xf[nt][ks]));   // opaque def: no remat possible

  // stage full slab fp32 -> bf16 (256 rows x 128), swizzled 16B chunks.
  // nt loads: slab is read-once, keep it from displacing wv in L2.
  const float* src = fc4 + ((size_t)(PHASE ? 65536 : 0) + (size_t)kcol * 256) * HPDIM;
  #pragma unroll
  for (int it = 0; it < 4; ++it) {
    int cidx = it * 1024 + t;              // 4096 chunks (256 rows x 16)
    int row = cidx >> 4, kb = cidx & 15;
    const float* s = src + cidx * 8;       // coalesced
    float4 a = ntload4(s), b = ntload4(s + 4);
    *(uint4*)(lds + row*256 + ((kb ^ (row & 7)) << 4)) = pack8u(a, b);
  }
  __syncthreads();

  float gacc[4] = {0.f, 0.f, 0.f, 0.f};
  const float* wbase = wTT + (size_t)quad * 4096 + (bw + r16) * 4;

  #pragma unroll 1
  for (int hg = 0; hg < 16; ++hg) {
    float4 wv[4];
    #pragma unroll
    for (int nt = 0; nt < 4; ++nt)         // L2 loads first (consumed post-MFMA)
      wv[nt] = *(const float4*)(wbase + (size_t)hg*16384 + nt*64);
    const int row = hg*16 + r16;
    bf8 af[4];
    #pragma unroll
    for (int ks = 0; ks < 4; ++ks)
      af[ks] = *(bf8*)(lds + row*256 + (((ks*4 + quad) ^ (row & 7)) << 4));
    #pragma unroll
    for (int nt = 0; nt < 4; ++nt) {
      f32x4 acc = {};
      #pragma unroll
      for (int ks = 0; ks < 4; ++ks)
        acc = __builtin_amdgcn_mfma_f32_16x16x32_bf16(af[ks], xf[nt][ks], acc, 0, 0, 0);
      gacc[nt] += acc[0]*wv[nt].x + acc[1]*wv[nt].y + acc[2]*wv[nt].z + acc[3]*wv[nt].w;
    }
  }

  #pragma unroll
  for (int nt = 0; nt < 4; ++nt) {
    float v = gacc[nt];
    v += __shfl_xor(v, 16);
    v += __shfl_xor(v, 32);
    if (quad == 0) {
      int b = bw + nt*16 + r16;
      if (PHASE == 0) outp[(size_t)(kcol >> 2)*4096 + b*4 + (kcol & 3)] = fast_tanh(v);
      else            outp[b*HDIM + kcol] = v;
    }
  }
}

extern "C" void kernel_launch(void* const* d_in, const int* in_sizes, int n_in,
                              void* d_out, int out_size, void* d_ws, size_t ws_size,
                              hipStream_t stream) {
  const float* h0  = (const float*)d_in[0];
  const float* htt = (const float*)d_in[1];
  const float* msg = (const float*)d_in[2];
  const float* c   = (const float*)d_in[3];
  const float* w1  = (const float*)d_in[4];
  const float* w2  = (const float*)d_in[5];
  const float* w3  = (const float*)d_in[6];
  const float* w4  = (const float*)d_in[7];
  float* out = (float*)d_out;

  short* x3f  = (short*)d_ws;                              // 256 KB
  float* g1TT = (float*)((char*)d_ws + 262144);            // 1 MB
  float* msgTT= (float*)((char*)d_ws + 262144 + 1048576);  // 1 MB

  k_prep<<<dim3(80), dim3(256), 0, stream>>>(h0, htt, c, w1, w2, w3, msg,
                                             x3f, msgTT);
  k_hyper<0><<<dim3(256), dim3(1024), 0, stream>>>(x3f, msgTT, w4, g1TT);
  k_hyper<1><<<dim3(256), dim3(1024), 0, stream>>>(x3f, g1TT, w4, out);
}

// Round 7
// 152.492 us; speedup vs baseline: 1.0789x; 1.0789x over previous
//
#include <hip/hip_runtime.h>
#include <hip/hip_bf16.h>

#define HDIM 256
#define HPDIM 128

typedef short bf8 __attribute__((ext_vector_type(8)));   // 8 bf16 in 4 VGPRs
typedef float f32x4 __attribute__((ext_vector_type(4)));

__device__ inline unsigned pkbf2(float a, float b) {
  float2 f; f.x = a; f.y = b;
  __hip_bfloat162 h = __float22bfloat162_rn(f);          // v_cvt_pk_bf16_f32 (RNE)
  unsigned u; __builtin_memcpy(&u, &h, 4); return u;
}
__device__ inline unsigned short bfbits(float v) {
  __hip_bfloat16 h = __float2bfloat16(v);
  unsigned short u; __builtin_memcpy(&u, &h, 2); return u;
}
__device__ inline uint4 pack8u(float4 a, float4 b) {
  uint4 r;
  r.x = pkbf2(a.x, a.y); r.y = pkbf2(a.z, a.w);
  r.z = pkbf2(b.x, b.y); r.w = pkbf2(b.z, b.w);
  return r;
}
__device__ inline float fast_tanh(float x) {
  float t = __expf(2.0f * x);
  return 1.0f - 2.0f * __builtin_amdgcn_rcpf(t + 1.0f);
}
// gather 8 consecutive fp32 weights -> bf16 MFMA fragment
__device__ inline bf8 wfrag(const float* __restrict__ s) {
  float4 a = *(const float4*)s, b = *(const float4*)(s + 4);
  uint4 u = pack8u(a, b);
  bf8 r; __builtin_memcpy(&r, &u, 16); return r;
}

// ---------------- Kernel 0: prep -----------------------------------------
// blocks 0..63 : front MLP (self-gathered weight fragments) -> x3f
// blocks 64..79: msg[b][h] -> msgTT[(h>>2)*4096 + b*4 + (h&3)]
__global__ __launch_bounds__(256) void k_prep(
    const float* __restrict__ h0, const float* __restrict__ htv,
    const float* __restrict__ cp,
    const float* __restrict__ w1, const float* __restrict__ w2,
    const float* __restrict__ w3, const float* __restrict__ msg,
    short* __restrict__ x3f, float* __restrict__ msgTT) {
  const int t = threadIdx.x;
  const int bx = blockIdx.x;

  if (bx >= 64) {                      // ---- msg transpose: 16 blocks
    const int b0 = (bx - 64) * 64;
    #pragma unroll
    for (int it = 0; it < 16; ++it) {
      int u = it * 256 + t;            // 4096 (g,b) float4 pairs
      int bl = u & 63, g = u >> 6;
      float4 v = *(const float4*)(msg + (size_t)(b0 + bl) * HDIM + g * 4);
      *(float4*)(msgTT + (size_t)g * 4096 + (b0 + bl) * 4) = v;   // coalesced write
    }
    return;
  }

  // ---- front MLP: 64 blocks x 16 b ----
  __shared__ char hbuf[8192];    // 16 x 256 bf16, swizzled 16B chunks
  __shared__ char xa[4096];      // 16 x 128 bf16, swizzled
  __shared__ char xb[4096];
  const int wave = t >> 6, lane = t & 63;
  const int r16 = lane & 15, quad = lane >> 4;
  const int b0 = bx * 16;
  const float cc = fminf(fmaxf(cp[0], 0.f), 1.f);

  // stage h = cc*h0+(1-cc)*ht (16x256)
  #pragma unroll
  for (int it = 0; it < 2; ++it) {
    int flat = it * 2048 + t * 8;
    int row = flat >> 8, col = flat & 255, kb = col >> 3;
    int gi = (b0 + row) * HDIM + col;
    float4 a = *(const float4*)(h0 + gi);
    float4 b = *(const float4*)(htv + gi);
    float4 va, vb;
    va.x = cc*a.x + (1.f-cc)*b.x; va.y = cc*a.y + (1.f-cc)*b.y;
    va.z = cc*a.z + (1.f-cc)*b.z; va.w = cc*a.w + (1.f-cc)*b.w;
    a = *(const float4*)(h0 + gi + 4); b = *(const float4*)(htv + gi + 4);
    vb.x = cc*a.x + (1.f-cc)*b.x; vb.y = cc*a.y + (1.f-cc)*b.y;
    vb.z = cc*a.z + (1.f-cc)*b.z; vb.w = cc*a.w + (1.f-cc)*b.w;
    *(uint4*)(hbuf + row*512 + ((kb ^ (row & 7)) << 4)) = pack8u(va, vb);
  }
  __syncthreads();

  // layer 1: [16 x 256] @ w1^T -> xa
  {
    f32x4 acc[2] = {};
    #pragma unroll
    for (int ks = 0; ks < 8; ++ks) {
      bf8 af = *(bf8*)(hbuf + r16*512 + (((ks*4 + quad) ^ (r16 & 7)) << 4));
      #pragma unroll
      for (int nt = 0; nt < 2; ++nt) {
        bf8 bw_ = wfrag(w1 + ((wave*2 + nt)*16 + r16) * 256 + ks*32 + quad*8);
        acc[nt] = __builtin_amdgcn_mfma_f32_16x16x32_bf16(af, bw_, acc[nt], 0, 0, 0);
      }
    }
    #pragma unroll
    for (int nt = 0; nt < 2; ++nt)
      #pragma unroll
      for (int i = 0; i < 4; ++i) {
        int row = quad*4 + i, col = wave*32 + nt*16 + r16;
        *(unsigned short*)(xa + row*256 + (((col >> 3) ^ (row & 7)) << 4) + ((col & 7) << 1))
            = bfbits(fast_tanh(acc[nt][i]));
      }
  }
  __syncthreads();
  // layer 2: xa @ w2^T -> xb
  {
    f32x4 acc[2] = {};
    #pragma unroll
    for (int ks = 0; ks < 4; ++ks) {
      bf8 af = *(bf8*)(xa + r16*256 + (((ks*4 + quad) ^ (r16 & 7)) << 4));
      #pragma unroll
      for (int nt = 0; nt < 2; ++nt) {
        bf8 bw_ = wfrag(w2 + ((wave*2 + nt)*16 + r16) * 128 + ks*32 + quad*8);
        acc[nt] = __builtin_amdgcn_mfma_f32_16x16x32_bf16(af, bw_, acc[nt], 0, 0, 0);
      }
    }
    #pragma unroll
    for (int nt = 0; nt < 2; ++nt)
      #pragma unroll
      for (int i = 0; i < 4; ++i) {
        int row = quad*4 + i, col = wave*32 + nt*16 + r16;
        *(unsigned short*)(xb + row*256 + (((col >> 3) ^ (row & 7)) << 4) + ((col & 7) << 1))
            = bfbits(fast_tanh(acc[nt][i]));
      }
  }
  __syncthreads();
  // layer 3: xb @ w3^T -> xa
  {
    f32x4 acc[2] = {};
    #pragma unroll
    for (int ks = 0; ks < 4; ++ks) {
      bf8 af = *(bf8*)(xb + r16*256 + (((ks*4 + quad) ^ (r16 & 7)) << 4));
      #pragma unroll
      for (int nt = 0; nt < 2; ++nt) {
        bf8 bw_ = wfrag(w3 + ((wave*2 + nt)*16 + r16) * 128 + ks*32 + quad*8);
        acc[nt] = __builtin_amdgcn_mfma_f32_16x16x32_bf16(af, bw_, acc[nt], 0, 0, 0);
      }
    }
    #pragma unroll
    for (int nt = 0; nt < 2; ++nt)
      #pragma unroll
      for (int i = 0; i < 4; ++i) {
        int row = quad*4 + i, col = wave*32 + nt*16 + r16;
        *(unsigned short*)(xa + row*256 + (((col >> 3) ^ (row & 7)) << 4) + ((col & 7) << 1))
            = bfbits(fast_tanh(acc[nt][i]));
      }
  }
  __syncthreads();
  // dump xa -> x3f in B-fragment order
  {
    int ks = t >> 6, l = t & 63, q2 = l >> 4, rr = l & 15;
    uint4 d = *(uint4*)(xa + rr*256 + (((ks*4 + q2) ^ (rr & 7)) << 4));
    *(uint4*)(x3f + (size_t)((bx*4 + ks)*64 + l)*8) = d;
  }
}

// ---------------- Kernel 1/2: fused hypernetwork GEMM --------------------
// PHASE 0: g1TT[k,b] = tanh( sum_h msgTT[h,b] * (fc4[kcol*256+h,:] . x3[b,:]) )
// PHASE 1: out[b,kcol] =     sum_k g1TT[k,b]  * (fc4[65536+kcol*256+k,:] . x3[b,:])
// Block = 2 kcols x 512 b (1024 thr, 16 waves x 32 b): every wv float4 read
// is shared by 2 kcols -> wv traffic 256->128 MB/dispatch (the measured
// bottleneck: wv is L3-served at ~10 TB/s because the slab stream thrashes
// L2). The 2 b-half blocks of a kcol-pair are pinned to the SAME XCD and
// run concurrently, so their identical 256 KB slab reads dedup in L2 and
// HBM still sees ~32 MB. xf pinned via opaque asm (no remat). LDS = 2
// bf16 slabs = 128 KB, 1 block/CU.
template<int PHASE>
__global__ __launch_bounds__(1024, 4) void k_hyper(
    const short* __restrict__ x3f, const float* __restrict__ wTT,
    const float* __restrict__ fc4, float* __restrict__ outp) {
  __shared__ char lds[131072];             // 2 x (256 rows x 256 B), xor-swizzled
  const int bxs = blockIdx.x;
  const int xcd = bxs & 7, idx = bxs >> 3;
  const int half = idx & 1;                // b-half
  const int pair = xcd * 16 + (idx >> 1);  // kcol-pair, 16 pairs per XCD
  const int kbase = pair * 2;
  const int t = threadIdx.x, wave = t >> 6, lane = t & 63;
  const int r16 = lane & 15, quad = lane >> 4;
  const int bw = half * 512 + wave * 32;   // this wave's 32-b slice

  // x3 B-fragments (8 x b128 per thread = 32 VGPRs), pinned live
  bf8 xf[2][4];
  #pragma unroll
  for (int nt = 0; nt < 2; ++nt) {
    int g = half*32 + wave*2 + nt;         // b-group of 16
    #pragma unroll
    for (int ks = 0; ks < 4; ++ks)
      xf[nt][ks] = *(const bf8*)(x3f + (size_t)((g*4 + ks)*64 + lane)*8);
  }
  #pragma unroll
  for (int nt = 0; nt < 2; ++nt)
    #pragma unroll
    for (int ks = 0; ks < 4; ++ks)
      asm volatile("" : "+v"(xf[nt][ks]));   // opaque def: no remat possible

  // stage BOTH kcol slabs fp32 -> bf16 (2 x 256 rows x 128), swizzled
  const float* src = fc4 + ((size_t)(PHASE ? 65536 : 0) + (size_t)kbase * 256) * HPDIM;
  #pragma unroll
  for (int it = 0; it < 8; ++it) {
    int cidx = it * 1024 + t;              // 8192 chunks across 2 slabs
    int s = cidx >> 12, c2 = cidx & 4095;
    int row = c2 >> 4, kb = c2 & 15;
    const float* sp = src + cidx * 8;      // slabs contiguous, coalesced
    float4 a = *(const float4*)sp, b = *(const float4*)(sp + 4);
    *(uint4*)(lds + s*65536 + row*256 + ((kb ^ (row & 7)) << 4)) = pack8u(a, b);
  }
  __syncthreads();

  float gacc[2][2] = {{0.f, 0.f}, {0.f, 0.f}};
  const float* wbase = wTT + (size_t)quad * 4096 + (bw + r16) * 4;

  #pragma unroll 1
  for (int hg = 0; hg < 16; ++hg) {
    float4 wv[2];
    #pragma unroll
    for (int nt = 0; nt < 2; ++nt)         // L2/L3 loads first (consumed post-MFMA)
      wv[nt] = *(const float4*)(wbase + (size_t)hg*16384 + nt*64);
    const int row = hg*16 + r16;
    bf8 af0[4], af1[4];
    #pragma unroll
    for (int ks = 0; ks < 4; ++ks) {
      af0[ks] = *(bf8*)(lds +         row*256 + (((ks*4 + quad) ^ (row & 7)) << 4));
      af1[ks] = *(bf8*)(lds + 65536 + row*256 + (((ks*4 + quad) ^ (row & 7)) << 4));
    }
    #pragma unroll
    for (int nt = 0; nt < 2; ++nt) {
      f32x4 a0 = {}, a1 = {};
      #pragma unroll
      for (int ks = 0; ks < 4; ++ks) {
        a0 = __builtin_amdgcn_mfma_f32_16x16x32_bf16(af0[ks], xf[nt][ks], a0, 0, 0, 0);
        a1 = __builtin_amdgcn_mfma_f32_16x16x32_bf16(af1[ks], xf[nt][ks], a1, 0, 0, 0);
      }
      gacc[0][nt] += a0[0]*wv[nt].x + a0[1]*wv[nt].y + a0[2]*wv[nt].z + a0[3]*wv[nt].w;
      gacc[1][nt] += a1[0]*wv[nt].x + a1[1]*wv[nt].y + a1[2]*wv[nt].z + a1[3]*wv[nt].w;
    }
  }

  #pragma unroll
  for (int s = 0; s < 2; ++s)
    #pragma unroll
    for (int nt = 0; nt < 2; ++nt) {
      float v = gacc[s][nt];
      v += __shfl_xor(v, 16);
      v += __shfl_xor(v, 32);
      if (quad == 0) {
        int b = bw + nt*16 + r16;
        int kcol = kbase + s;
        if (PHASE == 0) outp[(size_t)(kcol >> 2)*4096 + b*4 + (kcol & 3)] = fast_tanh(v);
        else            outp[b*HDIM + kcol] = v;
      }
    }
}

extern "C" void kernel_launch(void* const* d_in, const int* in_sizes, int n_in,
                              void* d_out, int out_size, void* d_ws, size_t ws_size,
                              hipStream_t stream) {
  const float* h0  = (const float*)d_in[0];
  const float* htt = (const float*)d_in[1];
  const float* msg = (const float*)d_in[2];
  const float* c   = (const float*)d_in[3];
  const float* w1  = (const float*)d_in[4];
  const float* w2  = (const float*)d_in[5];
  const float* w3  = (const float*)d_in[6];
  const float* w4  = (const float*)d_in[7];
  float* out = (float*)d_out;

  short* x3f  = (short*)d_ws;                              // 256 KB
  float* g1TT = (float*)((char*)d_ws + 262144);            // 1 MB
  float* msgTT= (float*)((char*)d_ws + 262144 + 1048576);  // 1 MB

  k_prep<<<dim3(80), dim3(256), 0, stream>>>(h0, htt, c, w1, w2, w3, msg,
                                             x3f, msgTT);
  k_hyper<0><<<dim3(256), dim3(1024), 0, stream>>>(x3f, msgTT, w4, g1TT);
  k_hyper<1><<<dim3(256), dim3(1024), 0, stream>>>(x3f, g1TT, w4, out);
}